// Round 12
// baseline (507.746 us; speedup 1.0000x reference)
//
#include <hip/hip_runtime.h>
#include <hip/hip_fp16.h>
#include <math.h>

// Problem constants (fixed by the reference setup_inputs)
#define D      64
#define L      4
#define R      5
#define BGRAPH 1024
#define CT     4096          // edges per coarse-binning block
#define INVCAP 12288         // LDS rank-inversion capacity (avg bucket ~6.1K)

typedef __attribute__((ext_vector_type(8))) short short8;
typedef __attribute__((ext_vector_type(4))) float f32x4;

__device__ __forceinline__ ushort f2bf(float f) {          // RTN-even fp32->bf16
    unsigned u = __float_as_uint(f);
    return (ushort)((u + 0x7FFFu + ((u >> 16) & 1u)) >> 16);
}
__device__ __forceinline__ float bf2f(ushort h) {
    return __uint_as_float(((unsigned)h) << 16);
}

// ================= two-level MSD sort by dst (no global atomics) =================
// coarse bucket = dst>>8 (196 buckets of 256 nodes); per-block LDS binning.
// pe[pos] = src(16b) | et<<16(3b) | (dst&255)<<19(8b)  -- full payload packed.

__global__ void coarse_hist(const int* __restrict__ dst, int* __restrict__ bh,
                            int E, int nbl) {
    __shared__ int cnt[256];
    cnt[threadIdx.x] = 0;
    __syncthreads();
    int base = blockIdx.x * CT;
    int end = base + CT < E ? base + CT : E;
    for (int i = base + threadIdx.x; i < end; i += 256)
        atomicAdd(&cnt[dst[i] >> 8], 1);
    __syncthreads();
    bh[threadIdx.x * nbl + blockIdx.x] = cnt[threadIdx.x];   // [bucket][block]
}

__global__ void scan1(const int* __restrict__ hist, int* __restrict__ offs,
                      int* __restrict__ bsums, int n) {
    __shared__ int tmp[256];
    int i = blockIdx.x * 256 + threadIdx.x;
    int v = (i < n) ? hist[i] : 0;
    tmp[threadIdx.x] = v;
    __syncthreads();
    for (int o = 1; o < 256; o <<= 1) {
        int t = 0;
        if (threadIdx.x >= o) t = tmp[threadIdx.x - o];
        __syncthreads();
        if (threadIdx.x >= o) tmp[threadIdx.x] += t;
        __syncthreads();
    }
    if (i < n) offs[i] = tmp[threadIdx.x] - v;   // exclusive
    if (threadIdx.x == 255) bsums[blockIdx.x] = tmp[255];
}

__global__ void scan2(int* __restrict__ bsums, int nb) {
    __shared__ int tmp[1024];
    int v = (threadIdx.x < nb) ? bsums[threadIdx.x] : 0;
    tmp[threadIdx.x] = v;
    __syncthreads();
    for (int o = 1; o < 1024; o <<= 1) {
        int t = 0;
        if (threadIdx.x >= o) t = tmp[threadIdx.x - o];
        __syncthreads();
        if (threadIdx.x >= o) tmp[threadIdx.x] += t;
        __syncthreads();
    }
    if (threadIdx.x < nb) bsums[threadIdx.x] = tmp[threadIdx.x] - v;  // exclusive
}

__global__ void scan3(int* __restrict__ offs, const int* __restrict__ bsums, int n) {
    int i = blockIdx.x * 256 + threadIdx.x;
    if (i < n) offs[i] += bsums[blockIdx.x];
}

__global__ void coarse_scatter(const int* __restrict__ dst, const int* __restrict__ src,
                               const int* __restrict__ et, const int* __restrict__ bh,
                               int* __restrict__ pe, int E, int nbl) {
    __shared__ int cur[256];
    cur[threadIdx.x] = bh[threadIdx.x * nbl + blockIdx.x];
    __syncthreads();
    int base = blockIdx.x * CT;
    int end = base + CT < E ? base + CT : E;
    for (int i = base + threadIdx.x; i < end; i += 256) {
        int d = dst[i];
        int pos = atomicAdd(&cur[d >> 8], 1);            // LDS atomic only
        pe[pos] = src[i] | (et[i] << 16) | ((d & 255) << 19);
    }
}

// fine pass: one block per coarse bucket; only touches pe[] (linear reads).
// Emits meta[pos] = src|et<<16 (4B) COALESCED, invcN[node][r] = 1/cnt(node,r),
// deg[node], and the 256-bin degree histogram (for degree-balanced gather).
__global__ __launch_bounds__(512)
void fine_sort(const int* __restrict__ pe, const int* __restrict__ bh,
               int* __restrict__ offs, int* __restrict__ meta,
               float* __restrict__ invcN, int* __restrict__ deg,
               int* __restrict__ dhist, int E, int nbl, int N) {
    __shared__ int cnt[256];
    __shared__ int pref[256];
    __shared__ int cur[256];
    __shared__ int cntR[256 * R];
    __shared__ int inv[INVCAP];
    int b = blockIdx.x, t = threadIdx.x;
    int rbeg = bh[b * nbl];
    int rend = (b == gridDim.x - 1) ? E : bh[(b + 1) * nbl];
    int sz = rend - rbeg;
    if (t < 256) { cnt[t] = 0; cur[t] = 0; }
    for (int k = t; k < 256 * R; k += 512) cntR[k] = 0;
    __syncthreads();
    // phase 1: counts per node and per (node, rel)
    for (int i = rbeg + t; i < rend; i += 512) {
        int pk = pe[i];
        int ln = (pk >> 19) & 255;
        atomicAdd(&cnt[ln], 1);
        atomicAdd(&cntR[ln * R + ((pk >> 16) & 7)], 1);
    }
    __syncthreads();
    // phase 2: scan 256 node counters; write offs/deg/dhist; invert counts -> invcN
    if (t < 256) pref[t] = cnt[t];
    __syncthreads();
    for (int o = 1; o < 256; o <<= 1) {
        int tv = 0;
        if (t >= o && t < 256) tv = pref[t - o];
        __syncthreads();
        if (t >= o && t < 256) pref[t] += tv;
        __syncthreads();
    }
    if (t < 256) {
        int node = b * 256 + t;
        if (node <= N) offs[node] = rbeg + pref[t] - cnt[t];  // b=195,t=80 -> offs[N]=E
        if (node < N) {
            deg[node] = cnt[t];
            atomicAdd(&dhist[cnt[t] < 255 ? cnt[t] : 255], 1);
        }
    }
    for (int k = t; k < 256 * R; k += 512) {
        int c = cntR[k];
        float ic = 1.0f / (float)(c > 0 ? c : 1);
        ((float*)cntR)[k] = ic;
        int node = b * 256 + k / R;
        if (node < N) invcN[(size_t)b * 256 * R + k] = ic;   // coalesced
    }
    __syncthreads();
    if (sz <= INVCAP) {
        // phase 3a: rank into LDS
        for (int i = rbeg + t; i < rend; i += 512) {
            int pk = pe[i];
            int ln = (pk >> 19) & 255;
            int lp = pref[ln] - cnt[ln] + atomicAdd(&cur[ln], 1);
            inv[lp] = pk;
        }
        __syncthreads();
        // phase 3b: coalesced payload emit (src | et<<16)
        for (int k = t; k < sz; k += 512)
            meta[rbeg + k] = inv[k] & 0x7FFFF;
    } else {
        // fallback (bucket too big for LDS): scattered writes, still correct
        for (int i = rbeg + t; i < rend; i += 512) {
            int pk = pe[i];
            int ln = (pk >> 19) & 255;
            int pos = rbeg + (pref[ln] - cnt[ln]) + atomicAdd(&cur[ln], 1);
            meta[pos] = pk & 0x7FFFF;
        }
    }
}

// ---- degree counting sort: scan 256 bins, then scatter nodes -> perm ----
__global__ void dscan(int* __restrict__ dhist, int* __restrict__ dofs,
                      int* __restrict__ dcur) {
    __shared__ int tmp[256];
    int t = threadIdx.x;
    int v = dhist[t];
    tmp[t] = v;
    __syncthreads();
    for (int o = 1; o < 256; o <<= 1) {
        int tv = 0;
        if (t >= o) tv = tmp[t - o];
        __syncthreads();
        if (t >= o) tmp[t] += tv;
        __syncthreads();
    }
    dofs[t] = tmp[t] - v;
    dcur[t] = tmp[t] - v;
}

__global__ void dscatter(const int* __restrict__ deg, int* __restrict__ dcur,
                         int* __restrict__ perm, int N) {
    int v = blockIdx.x * 256 + threadIdx.x;
    if (v >= N) return;
    int d = deg[v]; d = d < 255 ? d : 255;
    int pos = atomicAdd(&dcur[d], 1);
    perm[pos] = v;
}

// ---- M in split-bf16 B-fragment layout: [l][cg][kt][lane][8], k-rows = [B0|B1|root] ----
__global__ void buildMfrag(const float* __restrict__ basis, const float* __restrict__ root,
                           ushort* __restrict__ Mhi, ushort* __restrict__ Mlo) {
    int t = blockIdx.x * 256 + threadIdx.x;
    if (t >= L * 4 * 6 * 64 * 8) return;
    int j = t & 7;
    int lane = (t >> 3) & 63;
    int rem = t >> 9;              // ((l*4+cg)*6+kt)
    int kt = rem % 6;
    int lcg = rem / 6;
    int cg = lcg & 3, l = lcg >> 2;
    int k = kt * 32 + (lane >> 4) * 8 + j;
    int col = cg * 16 + (lane & 15);
    float val;
    if (k < 64)       val = basis[(((size_t)l * 2 + 0) * D + k) * D + col];
    else if (k < 128) val = basis[(((size_t)l * 2 + 1) * D + (k - 64)) * D + col];
    else              val = root[((size_t)l * D + (k - 128)) * D + col];
    ushort hi = f2bf(val);
    Mhi[t] = hi;
    Mlo[t] = f2bf(val - bf2f(hi));
}

// ---- x -> hf (fp16; one-hot so exact) ----
__global__ void copyX(const float* __restrict__ x, __half* __restrict__ hf, int NE) {
    int i = blockIdx.x * 256 + threadIdx.x;
    if (i >= NE) return;
    hf[i] = __float2half(x[i]);
}

// ---- gather: 4 nodes per wave (quarter-wave per node), degree-balanced via perm.
// Per-edge: 1 meta(4B) + 1 LDS wtab read (premultiplied comp*invc) + 1 row load
// (16 lanes x 8B = 128B; 4 rows per wave-VMEM). Writes Z[v][128] (z0|z1).
__global__ __launch_bounds__(256)
void gather_k(const int* __restrict__ offs, const int* __restrict__ meta,
              const float* __restrict__ invcN, const int* __restrict__ perm,
              const __half* __restrict__ hfin, const float* __restrict__ comp_l,
              float* __restrict__ Z, int N) {
    __shared__ int vperm[16];
    __shared__ float2 wnT[16][5];      // [node-in-block][rel]: comp[r]*invc(v,r)
    int tid = threadIdx.x;
    int vbase0 = blockIdx.x * 16;
    if (tid < 16)
        vperm[tid] = (vbase0 + tid < N) ? perm[vbase0 + tid] : -1;
    __syncthreads();
    if (tid < 16 * R) {
        int n = tid / R, r = tid % R;
        int v = vperm[n];
        float ic = (v >= 0) ? invcN[(size_t)v * R + r] : 0.f;
        wnT[n][r] = make_float2(comp_l[2 * r] * ic, comp_l[2 * r + 1] * ic);
    }
    __syncthreads();

    int wid = tid >> 6, lane = tid & 63;
    int n = lane >> 4, q = lane & 15;
    int nl = wid * 4 + n;
    int v = vperm[nl];
    bool vlive = v >= 0;
    int vc = vlive ? v : 0;
    int b = offs[vc];
    int e2 = vlive ? offs[vc + 1] : b;
    int len = e2 - b;
    int lmax = len;
    lmax = max(lmax, __shfl_xor(lmax, 16));
    lmax = max(lmax, __shfl_xor(lmax, 32));

    float s0[4] = {0.f, 0.f, 0.f, 0.f}, s1[4] = {0.f, 0.f, 0.f, 0.f};
    const float2* hf4 = (const float2*)hfin;
    #pragma unroll 4
    for (int it = 0; it < lmax; ++it) {
        int gi = b + it;
        bool live = it < len;
        gi = live ? gi : 0;
        int pk = meta[gi];                       // 16-lane broadcast per quarter
        int s = pk & 0xFFFF;
        int r = (pk >> 16) & 7;
        float2 wt = wnT[nl][r];                  // LDS broadcast within quarter
        float w0 = live ? wt.x : 0.f;
        float w1 = live ? wt.y : 0.f;
        float2 hv = hf4[(size_t)s * 16 + q];     // 4 rows x 128B per wave-VMEM
        __half2 ha = *(__half2*)&hv.x;
        __half2 hb = *(__half2*)&hv.y;
        float f0 = __low2float(ha), f1 = __high2float(ha);
        float f2 = __low2float(hb), f3 = __high2float(hb);
        s0[0] = fmaf(w0, f0, s0[0]); s0[1] = fmaf(w0, f1, s0[1]);
        s0[2] = fmaf(w0, f2, s0[2]); s0[3] = fmaf(w0, f3, s0[3]);
        s1[0] = fmaf(w1, f0, s1[0]); s1[1] = fmaf(w1, f1, s1[1]);
        s1[2] = fmaf(w1, f2, s1[2]); s1[3] = fmaf(w1, f3, s1[3]);
    }
    if (vlive) {
        f32x4 o0 = { s0[0], s0[1], s0[2], s0[3] };
        f32x4 o1 = { s1[0], s1[1], s1[2], s1[3] };
        *(f32x4*)(Z + (size_t)v * 128 + 4 * q)      = o0;   // dims 4q..4q+3
        *(f32x4*)(Z + (size_t)v * 128 + 64 + 4 * q) = o1;
    }
}

// ---- transform: tanh([z0|z1|h] @ M + bias) via split-bf16 MFMA ----
// z-part from Z[N][128] (fp32 -> split); h-part straight from hfin (fp16 -> split,
// EXACT since fp16 has 11-bit significand). Writes hfout (ping-pong) + g rows.
__global__ __launch_bounds__(256)
void transform_k(const float* __restrict__ Z, const __half* __restrict__ hfin,
                 const ushort* __restrict__ Mhi_l, const ushort* __restrict__ Mlo_l,
                 const float* __restrict__ bias_l, __half* __restrict__ hfout,
                 float* __restrict__ g, int l, int N) {
    int wid = threadIdx.x >> 6, lane = threadIdx.x & 63;
    int tile = blockIdx.x * 4 + wid;
    if (tile * 16 >= N) return;
    int m = lane & 15, lg = lane >> 4;
    int row = tile * 16 + m;
    int rowc = row < N ? row : N - 1;

    short8 ahi[6], alo[6];
    const float* arow = Z + (size_t)rowc * 128 + lg * 8;
    #pragma unroll
    for (int kt = 0; kt < 4; ++kt) {                  // z-part from Z
        f32x4 x0 = *(const f32x4*)(arow + kt * 32);
        f32x4 x1 = *(const f32x4*)(arow + kt * 32 + 4);
        union { short8 v; ushort u[8]; } H, Lw;
        #pragma unroll
        for (int q = 0; q < 8; ++q) {
            float f = q < 4 ? x0[q] : x1[q - 4];
            ushort hi = f2bf(f);
            H.u[q] = hi;
            Lw.u[q] = f2bf(f - bf2f(hi));
        }
        ahi[kt] = H.v;
        alo[kt] = Lw.v;
    }
    #pragma unroll
    for (int kt = 4; kt < 6; ++kt) {                  // h-part from hfin (exact split)
        const __half* hp = hfin + (size_t)rowc * D + (kt - 4) * 32 + lg * 8;
        short8 hraw = *(const short8*)hp;
        union { short8 v; ushort u[8]; } H, Lw;
        #pragma unroll
        for (int q = 0; q < 8; ++q) {
            __half_raw hr; hr.x = (unsigned short)hraw[q];
            float f = __half2float(*(__half*)&hr);
            ushort hi = f2bf(f);
            H.u[q] = hi;
            Lw.u[q] = f2bf(f - bf2f(hi));
        }
        ahi[kt] = H.v;
        alo[kt] = Lw.v;
    }

    #pragma unroll
    for (int cg = 0; cg < 4; ++cg) {
        int col = cg * 16 + m;
        float bv = bias_l[col];
        f32x4 acc = { bv, bv, bv, bv };
        #pragma unroll
        for (int kt = 0; kt < 6; ++kt) {
            size_t boff = ((size_t)(cg * 6 + kt) * 64 + lane) * 8;
            short8 bhi = *(const short8*)(Mhi_l + boff);
            short8 blo = *(const short8*)(Mlo_l + boff);
            acc = __builtin_amdgcn_mfma_f32_16x16x32_bf16(ahi[kt], bhi, acc, 0, 0, 0);
            acc = __builtin_amdgcn_mfma_f32_16x16x32_bf16(ahi[kt], blo, acc, 0, 0, 0);
            acc = __builtin_amdgcn_mfma_f32_16x16x32_bf16(alo[kt], bhi, acc, 0, 0, 0);
        }
        int rowbase = tile * 16 + lg * 4;      // C/D: col=lane&15, row=(lane>>4)*4+reg
        #pragma unroll
        for (int r = 0; r < 4; ++r) {
            int node = rowbase + r;
            if (node < N) {
                float tv = tanhf(acc[r]);
                hfout[(size_t)node * D + col] = __float2half(tv);
                if (node < BGRAPH)
                    g[(size_t)node * (2 * L * D) + l * D + col] = tv;
                else if (node < 2 * BGRAPH)
                    g[(size_t)(node - BGRAPH) * (2 * L * D) + L * D + l * D + col] = tv;
            }
        }
    }
}

// ---- final MLP: 4 rows per block; w1 streamed once per block ----
__global__ void mlp4(const float* __restrict__ g, const float* __restrict__ w1,
                     const float* __restrict__ b1, const float* __restrict__ w2,
                     const float* __restrict__ b2, float* __restrict__ out) {
    __shared__ float gl[4][512];
    __shared__ float red[2][4][128];
    int tid = threadIdx.x;
    int rowbase = blockIdx.x * 4;
    for (int i = tid; i < 4 * 512; i += 256)
        gl[i >> 9][i & 511] = g[(size_t)rowbase * 512 + i];
    __syncthreads();
    int t = tid & 127, kh = tid >> 7;
    float s0 = 0.f, s1 = 0.f, s2 = 0.f, s3 = 0.f;
    int k0 = kh * 256;
    #pragma unroll 4
    for (int k = k0; k < k0 + 256; ++k) {
        float wv = w1[k * 128 + t];
        s0 = fmaf(gl[0][k], wv, s0);
        s1 = fmaf(gl[1][k], wv, s1);
        s2 = fmaf(gl[2][k], wv, s2);
        s3 = fmaf(gl[3][k], wv, s3);
    }
    red[kh][0][t] = s0; red[kh][1][t] = s1; red[kh][2][t] = s2; red[kh][3][t] = s3;
    __syncthreads();
    if (kh == 0) {
        #pragma unroll
        for (int r = 0; r < 4; ++r)
            gl[r][t] = fmaxf(red[0][r][t] + red[1][r][t] + b1[t], 0.f) * w2[t];
    }
    __syncthreads();
    int w = tid >> 6, lane = tid & 63;
    float val = gl[w][lane] + gl[w][lane + 64];
    #pragma unroll
    for (int o = 32; o > 0; o >>= 1) val += __shfl_down(val, o);
    if (lane == 0) out[rowbase + w] = val + b2[0];
}

extern "C" void kernel_launch(void* const* d_in, const int* in_sizes, int n_in,
                              void* d_out, int out_size, void* d_ws, size_t ws_size,
                              hipStream_t stream) {
    const float* x     = (const float*)d_in[0];
    const float* basis = (const float*)d_in[1];
    const float* comp  = (const float*)d_in[2];
    const float* root  = (const float*)d_in[3];
    const float* bias  = (const float*)d_in[4];
    const float* w1    = (const float*)d_in[5];
    const float* b1    = (const float*)d_in[6];
    const float* w2    = (const float*)d_in[7];
    const float* b2    = (const float*)d_in[8];
    const int*   src   = (const int*)d_in[9];
    const int*   dst   = (const int*)d_in[10];
    const int*   et    = (const int*)d_in[11];
    float* out = (float*)d_out;

    const int N = in_sizes[0] / D;   // 50000
    const int E = in_sizes[9];       // 1200000

    const int nbl = (E + CT - 1) / CT;        // 293 coarse blocks
    const int nbh = 256 * nbl;                // bucket-major count array
    const int nbuck = (N + 255) / 256;        // 196 coarse buckets

    // workspace carve-out (~50 MB)
    char* p = (char*)d_ws;
    auto alloc = [&](size_t bytes) -> char* {
        char* q = p;
        p += (bytes + 255) & ~(size_t)255;
        return q;
    };
    int*    offsN = (int*)alloc((size_t)(N + 1) * 4);
    int*    bh    = (int*)alloc((size_t)(nbh + 1) * 4);
    int*    bsums = (int*)alloc(1024 * 4);
    int*    pe    = (int*)alloc((size_t)E * 4);
    int*    meta  = (int*)alloc((size_t)E * 4);
    float*  invcN = (float*)alloc((size_t)(nbuck * 256) * R * 4);
    int*    deg   = (int*)alloc((size_t)N * 4);
    int*    dhist = (int*)alloc(256 * 4);
    int*    dofs  = (int*)alloc(256 * 4);
    int*    dcur  = (int*)alloc(256 * 4);
    int*    perm  = (int*)alloc((size_t)N * 4);
    float*  Z     = (float*)alloc((size_t)N * 128 * 4);
    __half* hf0   = (__half*)alloc((size_t)N * D * 2);
    __half* hf1   = (__half*)alloc((size_t)N * D * 2);
    float*  gbuf  = (float*)alloc((size_t)BGRAPH * 2 * L * D * 4);
    ushort* Mhi   = (ushort*)alloc((size_t)L * 4 * 6 * 64 * 8 * 2);
    ushort* Mlo   = (ushort*)alloc((size_t)L * 4 * 6 * 64 * 8 * 2);

    // ---- sort phase: LDS binning only ----
    hipMemsetAsync(dhist, 0, 256 * 4, stream);
    coarse_hist<<<nbl, 256, 0, stream>>>(dst, bh, E, nbl);
    int nb = (nbh + 255) / 256;               // == nbl (nbh multiple of 256)
    scan1<<<nb, 256, 0, stream>>>(bh, bh, bsums, nbh);   // in-place exclusive ok
    scan2<<<1, 1024, 0, stream>>>(bsums, nb);
    scan3<<<nb, 256, 0, stream>>>(bh, bsums, nbh);
    coarse_scatter<<<nbl, 256, 0, stream>>>(dst, src, et, bh, pe, E, nbl);
    fine_sort<<<nbuck, 512, 0, stream>>>(pe, bh, offsN, meta, invcN, deg, dhist,
                                         E, nbl, N);
    // degree counting sort -> perm (balanced waves in gather)
    dscan<<<1, 256, 0, stream>>>(dhist, dofs, dcur);
    dscatter<<<(N + 255) / 256, 256, 0, stream>>>(deg, dcur, perm, N);

    buildMfrag<<<(L * 4 * 6 * 64 * 8 + 255) / 256, 256, 0, stream>>>(basis, root, Mhi, Mlo);
    copyX<<<(N * D + 255) / 256, 256, 0, stream>>>(x, hf0, N * D);

    // ---- layers (split; hf ping-pong) ----
    __half* hbuf[2] = { hf0, hf1 };
    int ggrid = (N + 15) / 16;           // 3125 (16 nodes per 4-wave block)
    int tgrid = ((N + 15) / 16 + 3) / 4; // 782
    for (int l = 0; l < L; ++l) {
        gather_k<<<ggrid, 256, 0, stream>>>(offsN, meta, invcN, perm, hbuf[l & 1],
                                            comp + (size_t)l * R * 2, Z, N);
        transform_k<<<tgrid, 256, 0, stream>>>(Z, hbuf[l & 1],
                                               Mhi + (size_t)l * 4 * 6 * 64 * 8,
                                               Mlo + (size_t)l * 4 * 6 * 64 * 8,
                                               bias + (size_t)l * D,
                                               hbuf[(l + 1) & 1], gbuf, l, N);
    }
    mlp4<<<BGRAPH / 4, 256, 0, stream>>>(gbuf, w1, b1, w2, b2, out);
}

// Round 13
// 247.174 us; speedup vs baseline: 2.0542x; 2.0542x over previous
//
#include <hip/hip_runtime.h>
#include <hip/hip_fp16.h>
#include <math.h>

// Problem constants (fixed by the reference setup_inputs)
#define D      64
#define L      4
#define R      5
#define BGRAPH 1024
#define CT     4096          // edges per coarse-binning block
#define INVCAP 12288         // LDS rank-inversion capacity (avg bucket ~6.1K)

typedef __attribute__((ext_vector_type(8))) short short8;
typedef __attribute__((ext_vector_type(4))) float f32x4;

__device__ __forceinline__ ushort f2bf(float f) {          // RTN-even fp32->bf16
    unsigned u = __float_as_uint(f);
    return (ushort)((u + 0x7FFFu + ((u >> 16) & 1u)) >> 16);
}
__device__ __forceinline__ float bf2f(ushort h) {
    return __uint_as_float(((unsigned)h) << 16);
}

// ================= two-level MSD sort by dst (no global atomics) =================
// coarse bucket = dst>>8 (196 buckets of 256 nodes); per-block LDS binning.
// pe[pos] = src(16b) | et<<16(3b) | (dst&255)<<19(8b)  -- full payload packed.

__global__ void coarse_hist(const int* __restrict__ dst, int* __restrict__ bh,
                            int E, int nbl) {
    __shared__ int cnt[256];
    cnt[threadIdx.x] = 0;
    __syncthreads();
    int base = blockIdx.x * CT;
    int end = base + CT < E ? base + CT : E;
    for (int i = base + threadIdx.x; i < end; i += 256)
        atomicAdd(&cnt[dst[i] >> 8], 1);
    __syncthreads();
    bh[threadIdx.x * nbl + blockIdx.x] = cnt[threadIdx.x];   // [bucket][block]
}

__global__ void scan1(const int* __restrict__ hist, int* __restrict__ offs,
                      int* __restrict__ bsums, int n) {
    __shared__ int tmp[256];
    int i = blockIdx.x * 256 + threadIdx.x;
    int v = (i < n) ? hist[i] : 0;
    tmp[threadIdx.x] = v;
    __syncthreads();
    for (int o = 1; o < 256; o <<= 1) {
        int t = 0;
        if (threadIdx.x >= o) t = tmp[threadIdx.x - o];
        __syncthreads();
        if (threadIdx.x >= o) tmp[threadIdx.x] += t;
        __syncthreads();
    }
    if (i < n) offs[i] = tmp[threadIdx.x] - v;   // exclusive
    if (threadIdx.x == 255) bsums[blockIdx.x] = tmp[255];
}

__global__ void scan2(int* __restrict__ bsums, int nb) {
    __shared__ int tmp[1024];
    int v = (threadIdx.x < nb) ? bsums[threadIdx.x] : 0;
    tmp[threadIdx.x] = v;
    __syncthreads();
    for (int o = 1; o < 1024; o <<= 1) {
        int t = 0;
        if (threadIdx.x >= o) t = tmp[threadIdx.x - o];
        __syncthreads();
        if (threadIdx.x >= o) tmp[threadIdx.x] += t;
        __syncthreads();
    }
    if (threadIdx.x < nb) bsums[threadIdx.x] = tmp[threadIdx.x] - v;  // exclusive
}

__global__ void scan3(int* __restrict__ offs, const int* __restrict__ bsums, int n) {
    int i = blockIdx.x * 256 + threadIdx.x;
    if (i < n) offs[i] += bsums[blockIdx.x];
}

__global__ void coarse_scatter(const int* __restrict__ dst, const int* __restrict__ src,
                               const int* __restrict__ et, const int* __restrict__ bh,
                               int* __restrict__ pe, int E, int nbl) {
    __shared__ int cur[256];
    cur[threadIdx.x] = bh[threadIdx.x * nbl + blockIdx.x];
    __syncthreads();
    int base = blockIdx.x * CT;
    int end = base + CT < E ? base + CT : E;
    for (int i = base + threadIdx.x; i < end; i += 256) {
        int d = dst[i];
        int pos = atomicAdd(&cur[d >> 8], 1);            // LDS atomic only
        pe[pos] = src[i] | (et[i] << 16) | ((d & 255) << 19);
    }
}

// fine pass: one block per coarse bucket; only touches pe[] (linear reads).
// Emits meta[pos] = src|et<<16 (4B) COALESCED, invcN[node][r] = 1/cnt(node,r),
// and deg[node] (plain store -- NO global atomics).
__global__ __launch_bounds__(512)
void fine_sort(const int* __restrict__ pe, const int* __restrict__ bh,
               int* __restrict__ offs, int* __restrict__ meta,
               float* __restrict__ invcN, int* __restrict__ deg,
               int E, int nbl, int N) {
    __shared__ int cnt[256];
    __shared__ int pref[256];
    __shared__ int cur[256];
    __shared__ int cntR[256 * R];
    __shared__ int inv[INVCAP];
    int b = blockIdx.x, t = threadIdx.x;
    int rbeg = bh[b * nbl];
    int rend = (b == gridDim.x - 1) ? E : bh[(b + 1) * nbl];
    int sz = rend - rbeg;
    if (t < 256) { cnt[t] = 0; cur[t] = 0; }
    for (int k = t; k < 256 * R; k += 512) cntR[k] = 0;
    __syncthreads();
    // phase 1: counts per node and per (node, rel)
    for (int i = rbeg + t; i < rend; i += 512) {
        int pk = pe[i];
        int ln = (pk >> 19) & 255;
        atomicAdd(&cnt[ln], 1);
        atomicAdd(&cntR[ln * R + ((pk >> 16) & 7)], 1);
    }
    __syncthreads();
    // phase 2: scan 256 node counters; write offs/deg; invert counts -> invcN
    if (t < 256) pref[t] = cnt[t];
    __syncthreads();
    for (int o = 1; o < 256; o <<= 1) {
        int tv = 0;
        if (t >= o && t < 256) tv = pref[t - o];
        __syncthreads();
        if (t >= o && t < 256) pref[t] += tv;
        __syncthreads();
    }
    if (t < 256) {
        int node = b * 256 + t;
        if (node <= N) offs[node] = rbeg + pref[t] - cnt[t];  // b=195,t=80 -> offs[N]=E
        if (node < N) deg[node] = cnt[t];
    }
    for (int k = t; k < 256 * R; k += 512) {
        int c = cntR[k];
        float ic = 1.0f / (float)(c > 0 ? c : 1);
        ((float*)cntR)[k] = ic;
        int node = b * 256 + k / R;
        if (node < N) invcN[(size_t)b * 256 * R + k] = ic;   // coalesced
    }
    __syncthreads();
    if (sz <= INVCAP) {
        // phase 3a: rank into LDS
        for (int i = rbeg + t; i < rend; i += 512) {
            int pk = pe[i];
            int ln = (pk >> 19) & 255;
            int lp = pref[ln] - cnt[ln] + atomicAdd(&cur[ln], 1);
            inv[lp] = pk;
        }
        __syncthreads();
        // phase 3b: coalesced payload emit (src | et<<16)
        for (int k = t; k < sz; k += 512)
            meta[rbeg + k] = inv[k] & 0x7FFFF;
    } else {
        // fallback (bucket too big for LDS): scattered writes, still correct
        for (int i = rbeg + t; i < rend; i += 512) {
            int pk = pe[i];
            int ln = (pk >> 19) & 255;
            int pos = rbeg + (pref[ln] - cnt[ln]) + atomicAdd(&cur[ln], 1);
            meta[pos] = pk & 0x7FFFF;
        }
    }
}

// ---- degree counting sort, contention-free (LDS binning + global scan) ----
__global__ void deg_hist(const int* __restrict__ deg, int* __restrict__ dh,
                         int N, int nblkD) {
    __shared__ int cnt[256];
    cnt[threadIdx.x] = 0;
    __syncthreads();
    int i = blockIdx.x * 256 + threadIdx.x;
    if (i < N) {
        int d = deg[i]; d = d < 255 ? d : 255;
        atomicAdd(&cnt[d], 1);                  // LDS atomic only
    }
    __syncthreads();
    dh[threadIdx.x * nblkD + blockIdx.x] = cnt[threadIdx.x];   // [bin][block]
}

__global__ void deg_scatter(const int* __restrict__ deg, const int* __restrict__ dh,
                            int* __restrict__ perm, int N, int nblkD) {
    __shared__ int cur[256];
    cur[threadIdx.x] = dh[threadIdx.x * nblkD + blockIdx.x];
    __syncthreads();
    int i = blockIdx.x * 256 + threadIdx.x;
    if (i < N) {
        int d = deg[i]; d = d < 255 ? d : 255;
        int pos = atomicAdd(&cur[d], 1);        // LDS atomic only
        perm[pos] = i;
    }
}

// ---- M in split-bf16 B-fragment layout: [l][cg][kt][lane][8], k-rows = [B0|B1|root] ----
__global__ void buildMfrag(const float* __restrict__ basis, const float* __restrict__ root,
                           ushort* __restrict__ Mhi, ushort* __restrict__ Mlo) {
    int t = blockIdx.x * 256 + threadIdx.x;
    if (t >= L * 4 * 6 * 64 * 8) return;
    int j = t & 7;
    int lane = (t >> 3) & 63;
    int rem = t >> 9;              // ((l*4+cg)*6+kt)
    int kt = rem % 6;
    int lcg = rem / 6;
    int cg = lcg & 3, l = lcg >> 2;
    int k = kt * 32 + (lane >> 4) * 8 + j;
    int col = cg * 16 + (lane & 15);
    float val;
    if (k < 64)       val = basis[(((size_t)l * 2 + 0) * D + k) * D + col];
    else if (k < 128) val = basis[(((size_t)l * 2 + 1) * D + (k - 64)) * D + col];
    else              val = root[((size_t)l * D + (k - 128)) * D + col];
    ushort hi = f2bf(val);
    Mhi[t] = hi;
    Mlo[t] = f2bf(val - bf2f(hi));
}

// ---- x -> hf (fp16; one-hot so exact) ----
__global__ void copyX(const float* __restrict__ x, __half* __restrict__ hf, int NE) {
    int i = blockIdx.x * 256 + threadIdx.x;
    if (i >= NE) return;
    hf[i] = __float2half(x[i]);
}

// ---- gather: 4 nodes per wave (quarter-wave per node), degree-balanced via perm.
// Per-edge: 1 meta(4B) + 1 LDS wtab read (premultiplied comp*invc) + 1 row load
// (16 lanes x 8B = 128B; 4 rows per wave-VMEM). Writes Z[v][128] (z0|z1).
__global__ __launch_bounds__(256)
void gather_k(const int* __restrict__ offs, const int* __restrict__ meta,
              const float* __restrict__ invcN, const int* __restrict__ perm,
              const __half* __restrict__ hfin, const float* __restrict__ comp_l,
              float* __restrict__ Z, int N) {
    __shared__ int vperm[16];
    __shared__ float2 wnT[16][5];      // [node-in-block][rel]: comp[r]*invc(v,r)
    int tid = threadIdx.x;
    int vbase0 = blockIdx.x * 16;
    if (tid < 16)
        vperm[tid] = (vbase0 + tid < N) ? perm[vbase0 + tid] : -1;
    __syncthreads();
    if (tid < 16 * R) {
        int n = tid / R, r = tid % R;
        int v = vperm[n];
        float ic = (v >= 0) ? invcN[(size_t)v * R + r] : 0.f;
        wnT[n][r] = make_float2(comp_l[2 * r] * ic, comp_l[2 * r + 1] * ic);
    }
    __syncthreads();

    int wid = tid >> 6, lane = tid & 63;
    int n = lane >> 4, q = lane & 15;
    int nl = wid * 4 + n;
    int v = vperm[nl];
    bool vlive = v >= 0;
    int vc = vlive ? v : 0;
    int b = offs[vc];
    int e2 = vlive ? offs[vc + 1] : b;
    int len = e2 - b;
    int lmax = len;
    lmax = max(lmax, __shfl_xor(lmax, 16));
    lmax = max(lmax, __shfl_xor(lmax, 32));

    float s0[4] = {0.f, 0.f, 0.f, 0.f}, s1[4] = {0.f, 0.f, 0.f, 0.f};
    const float2* hf4 = (const float2*)hfin;
    #pragma unroll 4
    for (int it = 0; it < lmax; ++it) {
        int gi = b + it;
        bool live = it < len;
        gi = live ? gi : 0;
        int pk = meta[gi];                       // 16-lane broadcast per quarter
        int s = pk & 0xFFFF;
        int r = (pk >> 16) & 7;
        float2 wt = wnT[nl][r];                  // LDS broadcast within quarter
        float w0 = live ? wt.x : 0.f;
        float w1 = live ? wt.y : 0.f;
        float2 hv = hf4[(size_t)s * 16 + q];     // 4 rows x 128B per wave-VMEM
        __half2 ha = *(__half2*)&hv.x;
        __half2 hb = *(__half2*)&hv.y;
        float f0 = __low2float(ha), f1 = __high2float(ha);
        float f2 = __low2float(hb), f3 = __high2float(hb);
        s0[0] = fmaf(w0, f0, s0[0]); s0[1] = fmaf(w0, f1, s0[1]);
        s0[2] = fmaf(w0, f2, s0[2]); s0[3] = fmaf(w0, f3, s0[3]);
        s1[0] = fmaf(w1, f0, s1[0]); s1[1] = fmaf(w1, f1, s1[1]);
        s1[2] = fmaf(w1, f2, s1[2]); s1[3] = fmaf(w1, f3, s1[3]);
    }
    if (vlive) {
        f32x4 o0 = { s0[0], s0[1], s0[2], s0[3] };
        f32x4 o1 = { s1[0], s1[1], s1[2], s1[3] };
        *(f32x4*)(Z + (size_t)v * 128 + 4 * q)      = o0;   // dims 4q..4q+3
        *(f32x4*)(Z + (size_t)v * 128 + 64 + 4 * q) = o1;
    }
}

// ---- transform: tanh([z0|z1|h] @ M + bias) via split-bf16 MFMA ----
// z-part from Z[N][128] (fp32 -> split); h-part straight from hfin (fp16 -> split,
// EXACT since fp16 has 11-bit significand). Writes hfout (ping-pong) + g rows.
__global__ __launch_bounds__(256)
void transform_k(const float* __restrict__ Z, const __half* __restrict__ hfin,
                 const ushort* __restrict__ Mhi_l, const ushort* __restrict__ Mlo_l,
                 const float* __restrict__ bias_l, __half* __restrict__ hfout,
                 float* __restrict__ g, int l, int N) {
    int wid = threadIdx.x >> 6, lane = threadIdx.x & 63;
    int tile = blockIdx.x * 4 + wid;
    if (tile * 16 >= N) return;
    int m = lane & 15, lg = lane >> 4;
    int row = tile * 16 + m;
    int rowc = row < N ? row : N - 1;

    short8 ahi[6], alo[6];
    const float* arow = Z + (size_t)rowc * 128 + lg * 8;
    #pragma unroll
    for (int kt = 0; kt < 4; ++kt) {                  // z-part from Z
        f32x4 x0 = *(const f32x4*)(arow + kt * 32);
        f32x4 x1 = *(const f32x4*)(arow + kt * 32 + 4);
        union { short8 v; ushort u[8]; } H, Lw;
        #pragma unroll
        for (int q = 0; q < 8; ++q) {
            float f = q < 4 ? x0[q] : x1[q - 4];
            ushort hi = f2bf(f);
            H.u[q] = hi;
            Lw.u[q] = f2bf(f - bf2f(hi));
        }
        ahi[kt] = H.v;
        alo[kt] = Lw.v;
    }
    #pragma unroll
    for (int kt = 4; kt < 6; ++kt) {                  // h-part from hfin (exact split)
        const __half* hp = hfin + (size_t)rowc * D + (kt - 4) * 32 + lg * 8;
        short8 hraw = *(const short8*)hp;
        union { short8 v; ushort u[8]; } H, Lw;
        #pragma unroll
        for (int q = 0; q < 8; ++q) {
            __half_raw hr; hr.x = (unsigned short)hraw[q];
            float f = __half2float(*(__half*)&hr);
            ushort hi = f2bf(f);
            H.u[q] = hi;
            Lw.u[q] = f2bf(f - bf2f(hi));
        }
        ahi[kt] = H.v;
        alo[kt] = Lw.v;
    }

    #pragma unroll
    for (int cg = 0; cg < 4; ++cg) {
        int col = cg * 16 + m;
        float bv = bias_l[col];
        f32x4 acc = { bv, bv, bv, bv };
        #pragma unroll
        for (int kt = 0; kt < 6; ++kt) {
            size_t boff = ((size_t)(cg * 6 + kt) * 64 + lane) * 8;
            short8 bhi = *(const short8*)(Mhi_l + boff);
            short8 blo = *(const short8*)(Mlo_l + boff);
            acc = __builtin_amdgcn_mfma_f32_16x16x32_bf16(ahi[kt], bhi, acc, 0, 0, 0);
            acc = __builtin_amdgcn_mfma_f32_16x16x32_bf16(ahi[kt], blo, acc, 0, 0, 0);
            acc = __builtin_amdgcn_mfma_f32_16x16x32_bf16(alo[kt], bhi, acc, 0, 0, 0);
        }
        int rowbase = tile * 16 + lg * 4;      // C/D: col=lane&15, row=(lane>>4)*4+reg
        #pragma unroll
        for (int r = 0; r < 4; ++r) {
            int node = rowbase + r;
            if (node < N) {
                float tv = tanhf(acc[r]);
                hfout[(size_t)node * D + col] = __float2half(tv);
                if (node < BGRAPH)
                    g[(size_t)node * (2 * L * D) + l * D + col] = tv;
                else if (node < 2 * BGRAPH)
                    g[(size_t)(node - BGRAPH) * (2 * L * D) + L * D + l * D + col] = tv;
            }
        }
    }
}

// ---- final MLP: 4 rows per block; w1 streamed once per block ----
__global__ void mlp4(const float* __restrict__ g, const float* __restrict__ w1,
                     const float* __restrict__ b1, const float* __restrict__ w2,
                     const float* __restrict__ b2, float* __restrict__ out) {
    __shared__ float gl[4][512];
    __shared__ float red[2][4][128];
    int tid = threadIdx.x;
    int rowbase = blockIdx.x * 4;
    for (int i = tid; i < 4 * 512; i += 256)
        gl[i >> 9][i & 511] = g[(size_t)rowbase * 512 + i];
    __syncthreads();
    int t = tid & 127, kh = tid >> 7;
    float s0 = 0.f, s1 = 0.f, s2 = 0.f, s3 = 0.f;
    int k0 = kh * 256;
    #pragma unroll 4
    for (int k = k0; k < k0 + 256; ++k) {
        float wv = w1[k * 128 + t];
        s0 = fmaf(gl[0][k], wv, s0);
        s1 = fmaf(gl[1][k], wv, s1);
        s2 = fmaf(gl[2][k], wv, s2);
        s3 = fmaf(gl[3][k], wv, s3);
    }
    red[kh][0][t] = s0; red[kh][1][t] = s1; red[kh][2][t] = s2; red[kh][3][t] = s3;
    __syncthreads();
    if (kh == 0) {
        #pragma unroll
        for (int r = 0; r < 4; ++r)
            gl[r][t] = fmaxf(red[0][r][t] + red[1][r][t] + b1[t], 0.f) * w2[t];
    }
    __syncthreads();
    int w = tid >> 6, lane = tid & 63;
    float val = gl[w][lane] + gl[w][lane + 64];
    #pragma unroll
    for (int o = 32; o > 0; o >>= 1) val += __shfl_down(val, o);
    if (lane == 0) out[rowbase + w] = val + b2[0];
}

extern "C" void kernel_launch(void* const* d_in, const int* in_sizes, int n_in,
                              void* d_out, int out_size, void* d_ws, size_t ws_size,
                              hipStream_t stream) {
    const float* x     = (const float*)d_in[0];
    const float* basis = (const float*)d_in[1];
    const float* comp  = (const float*)d_in[2];
    const float* root  = (const float*)d_in[3];
    const float* bias  = (const float*)d_in[4];
    const float* w1    = (const float*)d_in[5];
    const float* b1    = (const float*)d_in[6];
    const float* w2    = (const float*)d_in[7];
    const float* b2    = (const float*)d_in[8];
    const int*   src   = (const int*)d_in[9];
    const int*   dst   = (const int*)d_in[10];
    const int*   et    = (const int*)d_in[11];
    float* out = (float*)d_out;

    const int N = in_sizes[0] / D;   // 50000
    const int E = in_sizes[9];       // 1200000

    const int nbl = (E + CT - 1) / CT;        // 293 coarse blocks
    const int nbh = 256 * nbl;                // bucket-major count array
    const int nbuck = (N + 255) / 256;        // 196 coarse buckets
    const int nblkD = (N + 255) / 256;        // 196 degree-sort blocks
    const int ndh = 256 * nblkD;              // 50176

    // workspace carve-out (~50 MB)
    char* p = (char*)d_ws;
    auto alloc = [&](size_t bytes) -> char* {
        char* q = p;
        p += (bytes + 255) & ~(size_t)255;
        return q;
    };
    int*    offsN = (int*)alloc((size_t)(N + 1) * 4);
    int*    bh    = (int*)alloc((size_t)(nbh + 1) * 4);
    int*    bsums = (int*)alloc(1024 * 4);
    int*    pe    = (int*)alloc((size_t)E * 4);
    int*    meta  = (int*)alloc((size_t)E * 4);
    float*  invcN = (float*)alloc((size_t)(nbuck * 256) * R * 4);
    int*    deg   = (int*)alloc((size_t)N * 4);
    int*    dh    = (int*)alloc((size_t)ndh * 4);
    int*    perm  = (int*)alloc((size_t)N * 4);
    float*  Z     = (float*)alloc((size_t)N * 128 * 4);
    __half* hf0   = (__half*)alloc((size_t)N * D * 2);
    __half* hf1   = (__half*)alloc((size_t)N * D * 2);
    float*  gbuf  = (float*)alloc((size_t)BGRAPH * 2 * L * D * 4);
    ushort* Mhi   = (ushort*)alloc((size_t)L * 4 * 6 * 64 * 8 * 2);
    ushort* Mlo   = (ushort*)alloc((size_t)L * 4 * 6 * 64 * 8 * 2);

    // ---- sort phase: LDS binning only, no global atomics ----
    coarse_hist<<<nbl, 256, 0, stream>>>(dst, bh, E, nbl);
    int nb = (nbh + 255) / 256;               // == nbl (nbh multiple of 256)
    scan1<<<nb, 256, 0, stream>>>(bh, bh, bsums, nbh);   // in-place exclusive ok
    scan2<<<1, 1024, 0, stream>>>(bsums, nb);
    scan3<<<nb, 256, 0, stream>>>(bh, bsums, nbh);
    coarse_scatter<<<nbl, 256, 0, stream>>>(dst, src, et, bh, pe, E, nbl);
    fine_sort<<<nbuck, 512, 0, stream>>>(pe, bh, offsN, meta, invcN, deg, E, nbl, N);

    // degree counting sort -> perm (balanced waves in gather); LDS binning only
    deg_hist<<<nblkD, 256, 0, stream>>>(deg, dh, N, nblkD);
    int nb2 = (ndh + 255) / 256;              // == nblkD
    scan1<<<nb2, 256, 0, stream>>>(dh, dh, bsums, ndh);
    scan2<<<1, 1024, 0, stream>>>(bsums, nb2);
    scan3<<<nb2, 256, 0, stream>>>(dh, bsums, ndh);
    deg_scatter<<<nblkD, 256, 0, stream>>>(deg, dh, perm, N, nblkD);

    buildMfrag<<<(L * 4 * 6 * 64 * 8 + 255) / 256, 256, 0, stream>>>(basis, root, Mhi, Mlo);
    copyX<<<(N * D + 255) / 256, 256, 0, stream>>>(x, hf0, N * D);

    // ---- layers (split; hf ping-pong) ----
    __half* hbuf[2] = { hf0, hf1 };
    int ggrid = (N + 15) / 16;           // 3125 (16 nodes per 4-wave block)
    int tgrid = ((N + 15) / 16 + 3) / 4; // 782
    for (int l = 0; l < L; ++l) {
        gather_k<<<ggrid, 256, 0, stream>>>(offsN, meta, invcN, perm, hbuf[l & 1],
                                            comp + (size_t)l * R * 2, Z, N);
        transform_k<<<tgrid, 256, 0, stream>>>(Z, hbuf[l & 1],
                                               Mhi + (size_t)l * 4 * 6 * 64 * 8,
                                               Mlo + (size_t)l * 4 * 6 * 64 * 8,
                                               bias + (size_t)l * D,
                                               hbuf[(l + 1) & 1], gbuf, l, N);
    }
    mlp4<<<BGRAPH / 4, 256, 0, stream>>>(gbuf, w1, b1, w2, b2, out);
}

// Round 14
// 219.948 us; speedup vs baseline: 2.3085x; 1.1238x over previous
//
#include <hip/hip_runtime.h>
#include <hip/hip_fp16.h>
#include <math.h>

// Problem constants (fixed by the reference setup_inputs)
#define D      64
#define L      4
#define R      5
#define BGRAPH 1024
#define CT     4096          // edges per coarse-binning block
#define INVCAP 12288         // LDS rank-inversion capacity (avg bucket ~6.1K)

typedef __attribute__((ext_vector_type(8))) short short8;
typedef __attribute__((ext_vector_type(4))) float f32x4;

__device__ __forceinline__ ushort f2bf(float f) {          // RTN-even fp32->bf16
    unsigned u = __float_as_uint(f);
    return (ushort)((u + 0x7FFFu + ((u >> 16) & 1u)) >> 16);
}
__device__ __forceinline__ float bf2f(ushort h) {
    return __uint_as_float(((unsigned)h) << 16);
}

// ================= two-level MSD sort by dst (no global atomics) =================
// coarse bucket = dst>>8 (196 buckets of 256 nodes); per-block LDS binning.
// pe[pos] = src(16b) | et<<16(3b) | (dst&255)<<19(8b)  -- full payload packed.

__global__ void coarse_hist(const int* __restrict__ dst, int* __restrict__ bh,
                            int E, int nbl) {
    __shared__ int cnt[256];
    cnt[threadIdx.x] = 0;
    __syncthreads();
    int base = blockIdx.x * CT;
    int end = base + CT < E ? base + CT : E;
    for (int i = base + threadIdx.x; i < end; i += 256)
        atomicAdd(&cnt[dst[i] >> 8], 1);
    __syncthreads();
    bh[threadIdx.x * nbl + blockIdx.x] = cnt[threadIdx.x];   // [bucket][block]
}

__global__ void scan1(const int* __restrict__ hist, int* __restrict__ offs,
                      int* __restrict__ bsums, int n) {
    __shared__ int tmp[256];
    int i = blockIdx.x * 256 + threadIdx.x;
    int v = (i < n) ? hist[i] : 0;
    tmp[threadIdx.x] = v;
    __syncthreads();
    for (int o = 1; o < 256; o <<= 1) {
        int t = 0;
        if (threadIdx.x >= o) t = tmp[threadIdx.x - o];
        __syncthreads();
        if (threadIdx.x >= o) tmp[threadIdx.x] += t;
        __syncthreads();
    }
    if (i < n) offs[i] = tmp[threadIdx.x] - v;   // exclusive
    if (threadIdx.x == 255) bsums[blockIdx.x] = tmp[255];
}

__global__ void scan2(int* __restrict__ bsums, int nb) {
    __shared__ int tmp[1024];
    int v = (threadIdx.x < nb) ? bsums[threadIdx.x] : 0;
    tmp[threadIdx.x] = v;
    __syncthreads();
    for (int o = 1; o < 1024; o <<= 1) {
        int t = 0;
        if (threadIdx.x >= o) t = tmp[threadIdx.x - o];
        __syncthreads();
        if (threadIdx.x >= o) tmp[threadIdx.x] += t;
        __syncthreads();
    }
    if (threadIdx.x < nb) bsums[threadIdx.x] = tmp[threadIdx.x] - v;  // exclusive
}

__global__ void scan3(int* __restrict__ offs, const int* __restrict__ bsums, int n) {
    int i = blockIdx.x * 256 + threadIdx.x;
    if (i < n) offs[i] += bsums[blockIdx.x];
}

__global__ void coarse_scatter(const int* __restrict__ dst, const int* __restrict__ src,
                               const int* __restrict__ et, const int* __restrict__ bh,
                               int* __restrict__ pe, int E, int nbl) {
    __shared__ int cur[256];
    cur[threadIdx.x] = bh[threadIdx.x * nbl + blockIdx.x];
    __syncthreads();
    int base = blockIdx.x * CT;
    int end = base + CT < E ? base + CT : E;
    for (int i = base + threadIdx.x; i < end; i += 256) {
        int d = dst[i];
        int pos = atomicAdd(&cur[d >> 8], 1);            // LDS atomic only
        pe[pos] = src[i] | (et[i] << 16) | ((d & 255) << 19);
    }
}

// fine pass: one block per coarse bucket; only touches pe[] (linear reads).
// Emits meta[pos] = src|et<<16 (4B) COALESCED and invcN[node][r] = 1/cnt(node,r).
__global__ __launch_bounds__(512)
void fine_sort(const int* __restrict__ pe, const int* __restrict__ bh,
               int* __restrict__ offs, int* __restrict__ meta,
               float* __restrict__ invcN, int E, int nbl, int N) {
    __shared__ int cnt[256];
    __shared__ int pref[256];
    __shared__ int cur[256];
    __shared__ int cntR[256 * R];
    __shared__ int inv[INVCAP];
    int b = blockIdx.x, t = threadIdx.x;
    int rbeg = bh[b * nbl];
    int rend = (b == gridDim.x - 1) ? E : bh[(b + 1) * nbl];
    int sz = rend - rbeg;
    if (t < 256) { cnt[t] = 0; cur[t] = 0; }
    for (int k = t; k < 256 * R; k += 512) cntR[k] = 0;
    __syncthreads();
    // phase 1: counts per node and per (node, rel)
    for (int i = rbeg + t; i < rend; i += 512) {
        int pk = pe[i];
        int ln = (pk >> 19) & 255;
        atomicAdd(&cnt[ln], 1);
        atomicAdd(&cntR[ln * R + ((pk >> 16) & 7)], 1);
    }
    __syncthreads();
    // phase 2: scan 256 node counters; write offs; invert counts -> invcN
    if (t < 256) pref[t] = cnt[t];
    __syncthreads();
    for (int o = 1; o < 256; o <<= 1) {
        int tv = 0;
        if (t >= o && t < 256) tv = pref[t - o];
        __syncthreads();
        if (t >= o && t < 256) pref[t] += tv;
        __syncthreads();
    }
    if (t < 256) {
        int node = b * 256 + t;
        if (node <= N) offs[node] = rbeg + pref[t] - cnt[t];  // b=195,t=80 -> offs[N]=E
    }
    for (int k = t; k < 256 * R; k += 512) {
        int c = cntR[k];
        float ic = 1.0f / (float)(c > 0 ? c : 1);
        ((float*)cntR)[k] = ic;
        int node = b * 256 + k / R;
        if (node < N) invcN[(size_t)b * 256 * R + k] = ic;   // coalesced
    }
    __syncthreads();
    if (sz <= INVCAP) {
        // phase 3a: rank into LDS
        for (int i = rbeg + t; i < rend; i += 512) {
            int pk = pe[i];
            int ln = (pk >> 19) & 255;
            int lp = pref[ln] - cnt[ln] + atomicAdd(&cur[ln], 1);
            inv[lp] = pk;
        }
        __syncthreads();
        // phase 3b: coalesced payload emit (src | et<<16)
        for (int k = t; k < sz; k += 512)
            meta[rbeg + k] = inv[k] & 0x7FFFF;
    } else {
        // fallback (bucket too big for LDS): scattered writes, still correct
        for (int i = rbeg + t; i < rend; i += 512) {
            int pk = pe[i];
            int ln = (pk >> 19) & 255;
            int pos = rbeg + (pref[ln] - cnt[ln]) + atomicAdd(&cur[ln], 1);
            meta[pos] = pk & 0x7FFFF;
        }
    }
}

// ---- M in split-bf16 B-fragment layout: [l][cg][kt][lane][8], k-rows = [B0|B1|root] ----
__global__ void buildMfrag(const float* __restrict__ basis, const float* __restrict__ root,
                           ushort* __restrict__ Mhi, ushort* __restrict__ Mlo) {
    int t = blockIdx.x * 256 + threadIdx.x;
    if (t >= L * 4 * 6 * 64 * 8) return;
    int j = t & 7;
    int lane = (t >> 3) & 63;
    int rem = t >> 9;              // ((l*4+cg)*6+kt)
    int kt = rem % 6;
    int lcg = rem / 6;
    int cg = lcg & 3, l = lcg >> 2;
    int k = kt * 32 + (lane >> 4) * 8 + j;
    int col = cg * 16 + (lane & 15);
    float val;
    if (k < 64)       val = basis[(((size_t)l * 2 + 0) * D + k) * D + col];
    else if (k < 128) val = basis[(((size_t)l * 2 + 1) * D + (k - 64)) * D + col];
    else              val = root[((size_t)l * D + (k - 128)) * D + col];
    ushort hi = f2bf(val);
    Mhi[t] = hi;
    Mlo[t] = f2bf(val - bf2f(hi));
}

// ---- x -> hf (fp16; one-hot so exact) ----
__global__ void copyX(const float* __restrict__ x, __half* __restrict__ hf, int NE) {
    int i = blockIdx.x * 256 + threadIdx.x;
    if (i >= NE) return;
    hf[i] = __float2half(x[i]);
}

// ---- gather: 4 nodes x 2 edge-slots x 8 dim-octets per wave.
// Each lane loads float4 (8 halves, 16B) of its edge's row: one VMEM pair covers
// 8 edges (meta: 8-lane-broadcast dword; hf: 8 rows = 1KB). Per-node weights
// premultiplied in LDS. One shfl_xor(32) round combines the 2 edge slots.
__global__ __launch_bounds__(256)
void gather_k(const int* __restrict__ offs, const int* __restrict__ meta,
              const float* __restrict__ invcN, const __half* __restrict__ hfin,
              const float* __restrict__ comp_l, float* __restrict__ Z, int N) {
    __shared__ float2 wnT[16][5];      // [node-in-block][rel]: comp[r]*invc(v,r)
    int tid = threadIdx.x;
    int vbase0 = blockIdx.x * 16;
    if (tid < 16 * R) {
        int n = tid / R, r = tid % R;
        int v = vbase0 + n;
        float ic = (v < N) ? invcN[(size_t)v * R + r] : 0.f;
        wnT[n][r] = make_float2(comp_l[2 * r] * ic, comp_l[2 * r + 1] * ic);
    }
    __syncthreads();

    int wid = tid >> 6, lane = tid & 63;
    int h = lane >> 5;                 // edge slot (0/1)
    int n = (lane >> 3) & 3;           // node within wave
    int q = lane & 7;                  // dim octet
    int nl = wid * 4 + n;
    int v = vbase0 + nl;
    bool vlive = v < N;
    int vc = vlive ? v : 0;
    int b = offs[vc];
    int e2 = vlive ? offs[vc + 1] : b;
    int len = e2 - b;
    int lmax = len;                    // max over the wave's 4 nodes (lane bits 3,4)
    lmax = max(lmax, __shfl_xor(lmax, 8));
    lmax = max(lmax, __shfl_xor(lmax, 16));
    int nits = (lmax + 1) >> 1;

    float s0[8] = {0,0,0,0,0,0,0,0}, s1[8] = {0,0,0,0,0,0,0,0};
    const float4* hf16 = (const float4*)hfin;   // 16B units; row = 8 units
    #pragma unroll 4
    for (int it = 0; it < nits; ++it) {
        int e = it * 2 + h;
        bool live = e < len;
        int gi = live ? (b + e) : 0;
        int pk = meta[gi];                       // 8-lane broadcast groups
        int s = pk & 0xFFFF;
        int r = (pk >> 16) & 7;
        float2 wt = wnT[nl][r];                  // LDS broadcast within octet
        float w0 = live ? wt.x : 0.f;
        float w1 = live ? wt.y : 0.f;
        float4 hv = hf16[(size_t)s * 8 + q];     // 8 rows x 128B per wave-VMEM
        const __half2* hp = (const __half2*)&hv;
        #pragma unroll
        for (int k2 = 0; k2 < 4; ++k2) {
            float lo = __low2float(hp[k2]), hi = __high2float(hp[k2]);
            s0[2 * k2]     = fmaf(w0, lo, s0[2 * k2]);
            s0[2 * k2 + 1] = fmaf(w0, hi, s0[2 * k2 + 1]);
            s1[2 * k2]     = fmaf(w1, lo, s1[2 * k2]);
            s1[2 * k2 + 1] = fmaf(w1, hi, s1[2 * k2 + 1]);
        }
    }
    #pragma unroll
    for (int k = 0; k < 8; ++k) {                // combine the 2 edge slots
        s0[k] += __shfl_xor(s0[k], 32);
        s1[k] += __shfl_xor(s1[k], 32);
    }
    if (vlive && h == 0) {                       // dims 8q..8q+7
        f32x4 a0 = { s0[0], s0[1], s0[2], s0[3] };
        f32x4 a1 = { s0[4], s0[5], s0[6], s0[7] };
        f32x4 c0 = { s1[0], s1[1], s1[2], s1[3] };
        f32x4 c1 = { s1[4], s1[5], s1[6], s1[7] };
        *(f32x4*)(Z + (size_t)v * 128 + 8 * q)          = a0;
        *(f32x4*)(Z + (size_t)v * 128 + 8 * q + 4)      = a1;
        *(f32x4*)(Z + (size_t)v * 128 + 64 + 8 * q)     = c0;
        *(f32x4*)(Z + (size_t)v * 128 + 64 + 8 * q + 4) = c1;
    }
}

// ---- transform: tanh([z0|z1|h] @ M + bias) via split-bf16 MFMA ----
// z-part from Z[N][128] (fp32 -> split); h-part straight from hfin (fp16 -> split,
// EXACT since fp16 has 11-bit significand). Writes hfout (ping-pong) + g rows.
__global__ __launch_bounds__(256)
void transform_k(const float* __restrict__ Z, const __half* __restrict__ hfin,
                 const ushort* __restrict__ Mhi_l, const ushort* __restrict__ Mlo_l,
                 const float* __restrict__ bias_l, __half* __restrict__ hfout,
                 float* __restrict__ g, int l, int N) {
    int wid = threadIdx.x >> 6, lane = threadIdx.x & 63;
    int tile = blockIdx.x * 4 + wid;
    if (tile * 16 >= N) return;
    int m = lane & 15, lg = lane >> 4;
    int row = tile * 16 + m;
    int rowc = row < N ? row : N - 1;

    short8 ahi[6], alo[6];
    const float* arow = Z + (size_t)rowc * 128 + lg * 8;
    #pragma unroll
    for (int kt = 0; kt < 4; ++kt) {                  // z-part from Z
        f32x4 x0 = *(const f32x4*)(arow + kt * 32);
        f32x4 x1 = *(const f32x4*)(arow + kt * 32 + 4);
        union { short8 v; ushort u[8]; } H, Lw;
        #pragma unroll
        for (int q = 0; q < 8; ++q) {
            float f = q < 4 ? x0[q] : x1[q - 4];
            ushort hi = f2bf(f);
            H.u[q] = hi;
            Lw.u[q] = f2bf(f - bf2f(hi));
        }
        ahi[kt] = H.v;
        alo[kt] = Lw.v;
    }
    #pragma unroll
    for (int kt = 4; kt < 6; ++kt) {                  // h-part from hfin (exact split)
        const __half* hp = hfin + (size_t)rowc * D + (kt - 4) * 32 + lg * 8;
        short8 hraw = *(const short8*)hp;
        union { short8 v; ushort u[8]; } H, Lw;
        #pragma unroll
        for (int q = 0; q < 8; ++q) {
            __half_raw hr; hr.x = (unsigned short)hraw[q];
            float f = __half2float(*(__half*)&hr);
            ushort hi = f2bf(f);
            H.u[q] = hi;
            Lw.u[q] = f2bf(f - bf2f(hi));
        }
        ahi[kt] = H.v;
        alo[kt] = Lw.v;
    }

    #pragma unroll
    for (int cg = 0; cg < 4; ++cg) {
        int col = cg * 16 + m;
        float bv = bias_l[col];
        f32x4 acc = { bv, bv, bv, bv };
        #pragma unroll
        for (int kt = 0; kt < 6; ++kt) {
            size_t boff = ((size_t)(cg * 6 + kt) * 64 + lane) * 8;
            short8 bhi = *(const short8*)(Mhi_l + boff);
            short8 blo = *(const short8*)(Mlo_l + boff);
            acc = __builtin_amdgcn_mfma_f32_16x16x32_bf16(ahi[kt], bhi, acc, 0, 0, 0);
            acc = __builtin_amdgcn_mfma_f32_16x16x32_bf16(ahi[kt], blo, acc, 0, 0, 0);
            acc = __builtin_amdgcn_mfma_f32_16x16x32_bf16(alo[kt], bhi, acc, 0, 0, 0);
        }
        int rowbase = tile * 16 + lg * 4;      // C/D: col=lane&15, row=(lane>>4)*4+reg
        #pragma unroll
        for (int r = 0; r < 4; ++r) {
            int node = rowbase + r;
            if (node < N) {
                float tv = tanhf(acc[r]);
                hfout[(size_t)node * D + col] = __float2half(tv);
                if (node < BGRAPH)
                    g[(size_t)node * (2 * L * D) + l * D + col] = tv;
                else if (node < 2 * BGRAPH)
                    g[(size_t)(node - BGRAPH) * (2 * L * D) + L * D + l * D + col] = tv;
            }
        }
    }
}

// ---- final MLP: 4 rows per block; w1 streamed once per block ----
__global__ void mlp4(const float* __restrict__ g, const float* __restrict__ w1,
                     const float* __restrict__ b1, const float* __restrict__ w2,
                     const float* __restrict__ b2, float* __restrict__ out) {
    __shared__ float gl[4][512];
    __shared__ float red[2][4][128];
    int tid = threadIdx.x;
    int rowbase = blockIdx.x * 4;
    for (int i = tid; i < 4 * 512; i += 256)
        gl[i >> 9][i & 511] = g[(size_t)rowbase * 512 + i];
    __syncthreads();
    int t = tid & 127, kh = tid >> 7;
    float s0 = 0.f, s1 = 0.f, s2 = 0.f, s3 = 0.f;
    int k0 = kh * 256;
    #pragma unroll 4
    for (int k = k0; k < k0 + 256; ++k) {
        float wv = w1[k * 128 + t];
        s0 = fmaf(gl[0][k], wv, s0);
        s1 = fmaf(gl[1][k], wv, s1);
        s2 = fmaf(gl[2][k], wv, s2);
        s3 = fmaf(gl[3][k], wv, s3);
    }
    red[kh][0][t] = s0; red[kh][1][t] = s1; red[kh][2][t] = s2; red[kh][3][t] = s3;
    __syncthreads();
    if (kh == 0) {
        #pragma unroll
        for (int r = 0; r < 4; ++r)
            gl[r][t] = fmaxf(red[0][r][t] + red[1][r][t] + b1[t], 0.f) * w2[t];
    }
    __syncthreads();
    int w = tid >> 6, lane = tid & 63;
    float val = gl[w][lane] + gl[w][lane + 64];
    #pragma unroll
    for (int o = 32; o > 0; o >>= 1) val += __shfl_down(val, o);
    if (lane == 0) out[rowbase + w] = val + b2[0];
}

extern "C" void kernel_launch(void* const* d_in, const int* in_sizes, int n_in,
                              void* d_out, int out_size, void* d_ws, size_t ws_size,
                              hipStream_t stream) {
    const float* x     = (const float*)d_in[0];
    const float* basis = (const float*)d_in[1];
    const float* comp  = (const float*)d_in[2];
    const float* root  = (const float*)d_in[3];
    const float* bias  = (const float*)d_in[4];
    const float* w1    = (const float*)d_in[5];
    const float* b1    = (const float*)d_in[6];
    const float* w2    = (const float*)d_in[7];
    const float* b2    = (const float*)d_in[8];
    const int*   src   = (const int*)d_in[9];
    const int*   dst   = (const int*)d_in[10];
    const int*   et    = (const int*)d_in[11];
    float* out = (float*)d_out;

    const int N = in_sizes[0] / D;   // 50000
    const int E = in_sizes[9];       // 1200000

    const int nbl = (E + CT - 1) / CT;        // 293 coarse blocks
    const int nbh = 256 * nbl;                // bucket-major count array
    const int nbuck = (N + 255) / 256;        // 196 coarse buckets

    // workspace carve-out (~48 MB)
    char* p = (char*)d_ws;
    auto alloc = [&](size_t bytes) -> char* {
        char* q = p;
        p += (bytes + 255) & ~(size_t)255;
        return q;
    };
    int*    offsN = (int*)alloc((size_t)(N + 1) * 4);
    int*    bh    = (int*)alloc((size_t)(nbh + 1) * 4);
    int*    bsums = (int*)alloc(1024 * 4);
    int*    pe    = (int*)alloc((size_t)E * 4);
    int*    meta  = (int*)alloc((size_t)E * 4);
    float*  invcN = (float*)alloc((size_t)(nbuck * 256) * R * 4);
    float*  Z     = (float*)alloc((size_t)N * 128 * 4);
    __half* hf0   = (__half*)alloc((size_t)N * D * 2);
    __half* hf1   = (__half*)alloc((size_t)N * D * 2);
    float*  gbuf  = (float*)alloc((size_t)BGRAPH * 2 * L * D * 4);
    ushort* Mhi   = (ushort*)alloc((size_t)L * 4 * 6 * 64 * 8 * 2);
    ushort* Mlo   = (ushort*)alloc((size_t)L * 4 * 6 * 64 * 8 * 2);

    // ---- sort phase: LDS binning only, no global atomics ----
    coarse_hist<<<nbl, 256, 0, stream>>>(dst, bh, E, nbl);
    int nb = (nbh + 255) / 256;               // == nbl (nbh multiple of 256)
    scan1<<<nb, 256, 0, stream>>>(bh, bh, bsums, nbh);   // in-place exclusive ok
    scan2<<<1, 1024, 0, stream>>>(bsums, nb);
    scan3<<<nb, 256, 0, stream>>>(bh, bsums, nbh);
    coarse_scatter<<<nbl, 256, 0, stream>>>(dst, src, et, bh, pe, E, nbl);
    fine_sort<<<nbuck, 512, 0, stream>>>(pe, bh, offsN, meta, invcN, E, nbl, N);

    buildMfrag<<<(L * 4 * 6 * 64 * 8 + 255) / 256, 256, 0, stream>>>(basis, root, Mhi, Mlo);
    copyX<<<(N * D + 255) / 256, 256, 0, stream>>>(x, hf0, N * D);

    // ---- layers (split; hf ping-pong) ----
    __half* hbuf[2] = { hf0, hf1 };
    int ggrid = (N + 15) / 16;           // 3125 (16 nodes per 4-wave block)
    int tgrid = ((N + 15) / 16 + 3) / 4; // 782
    for (int l = 0; l < L; ++l) {
        gather_k<<<ggrid, 256, 0, stream>>>(offsN, meta, invcN, hbuf[l & 1],
                                            comp + (size_t)l * R * 2, Z, N);
        transform_k<<<tgrid, 256, 0, stream>>>(Z, hbuf[l & 1],
                                               Mhi + (size_t)l * 4 * 6 * 64 * 8,
                                               Mlo + (size_t)l * 4 * 6 * 64 * 8,
                                               bias + (size_t)l * D,
                                               hbuf[(l + 1) & 1], gbuf, l, N);
    }
    mlp4<<<BGRAPH / 4, 256, 0, stream>>>(gbuf, w1, b1, w2, b2, out);
}